// Round 6
// baseline (102.349 us; speedup 1.0000x reference)
//
#include <hip/hip_runtime.h>

// Problem constants: B=16 batches, A=5 agents, C=512 channels, H=W=16.
#define NB 16
#define NA 5
#define NC 512
#define HW 256
#define NGQ 128                 // 4-channel groups
#define NTOT (NA * NB * NGQ)    // 10240 wave-items
#define NBLK 1024               // 4 blocks/CU (LDS-limited) -> fully resident
#define NWAVES (NBLK * 4)       // 4096 waves

typedef float f4 __attribute__((ext_vector_type(4)));
typedef _Float16 h4 __attribute__((ext_vector_type(4)));   // 8 B = ds b64

static __device__ __forceinline__ h4 splat4h(float v) {
    const _Float16 h = (_Float16)v;
    h4 r = {h, h, h, h};
    return r;
}

// Wave-self-contained fusion: each WAVE (not block) owns an item (i,b,4ch).
// Lane owns pixel quad [4*lane, 4*lane+3] (row-aligned). All LDS traffic is
// produced and consumed by the same wave => NO s_barrier anywhere; ordering
// is program order + compiler lgkmcnt + wave_barrier (codegen-only fence).
// Exact two-stage warp: rotation grid_sample -> fr (LDS) -> translation
// grid_sample -> accumulate. fp16 taps; residual exact f32.
__global__ __launch_bounds__(256) void fafmimo_wave_kernel(
    const float* __restrict__ feat,   // [A*B][C][256], feat[a*B+b] = local[b][a]
    const float* __restrict__ trans,  // [B][A][A][4][4]
    const int*   __restrict__ numa,   // [B][A], use [:,0]
    float*       __restrict__ out)    // [A*B][C][256]
{
    __shared__ h4 lds_slab[4][4][HW]; // 32 KiB: [wave][slot][pixel]
    __shared__ h4 lds_fr[4][HW];      //  8 KiB: [wave][pixel]

    const int w    = threadIdx.x >> 6;
    const int lane = threadIdx.x & 63;
    const int px0  = lane << 2;          // quad base pixel (contiguous in x)
    const int qy   = px0 >> 4;
    const int qx   = px0 & 15;           // quad x = qx..qx+3, one row
    const float fy = (float)qy - 7.5f;

    h4* const slab_w = &lds_slab[w][0][0];
    h4* const fr_w   = &lds_fr[w][0];
    const int wgid = blockIdx.x * 4 + w;

    for (int it = 0; it < 3; ++it) {
        const int idx = wgid + it * NWAVES;
        if (idx >= NTOT) break;          // wave-uniform
        const int g  = idx & (NGQ - 1);
        const int r  = idx >> 7;
        const int i  = r % NA;
        const int b  = r / NA;
        const int c0 = g << 2;
        const int n  = numa[b * NA];     // wave-uniform
        const bool work = (i < n) && (n > 1);

        // Residual, exact f32: acc[k] = quad pixels of channel c0+k (dwordx4).
        const float* own = feat + (size_t)((i * NB + b) * NC + c0) * HW + px0;
        f4 acc[4];
#pragma unroll
        for (int k = 0; k < 4; ++k) acc[k] = *(const f4*)(own + k * HW);

        if (work) {
            // ---- stage neighbor slabs (fp16, pixel-major h4) ----
#pragma unroll
            for (int jj = 0; jj < 4; ++jj) {
                const int j = jj + (jj >= i);
                if (j < n) {             // wave-uniform
                    const float* src = feat + (size_t)((j * NB + b) * NC + c0) * HW + px0;
                    f4 v[4];
#pragma unroll
                    for (int k = 0; k < 4; ++k) v[k] = *(const f4*)(src + k * HW);
#pragma unroll
                    for (int q = 0; q < 4; ++q) {
                        h4 hv = { (_Float16)v[0][q], (_Float16)v[1][q],
                                  (_Float16)v[2][q], (_Float16)v[3][q] };
                        slab_w[jj * HW + px0 + q] = hv;
                    }
                }
            }
            __builtin_amdgcn_wave_barrier();  // writes ordered before gathers

            h4 pair_acc[4] = {splat4h(0.f), splat4h(0.f), splat4h(0.f), splat4h(0.f)};

#pragma unroll
            for (int jj = 0; jj < 4; ++jj) {
                const int j = jj + (jj >= i);
                if (j < n) {
                    const float* tb = trans + (size_t)(((b * NA) + i) * NA + j) * 16;
                    const f4 row0 = *(const f4*)tb;        // r00 r01 _ tx
                    const f4 row1 = *(const f4*)(tb + 4);  // r10 r11 _ ty
                    const float r00 = row0.x, r01 = row0.y;
                    const float r10 = row1.x, r11 = row1.y;
                    const h4* sj = slab_w + jj * HW;

                    // ---- stage 1: rotation sample at lane's 4 pixels -> fr ----
#pragma unroll
                    for (int q = 0; q < 4; ++q) {
                        const float fx = (float)(qx + q) - 7.5f;
                        const float ixr = r00 * fx + r01 * fy + 7.5f;
                        const float iyr = r10 * fx + r11 * fy + 7.5f;
                        const float fx0 = floorf(ixr), fy0 = floorf(iyr);
                        const float wx1 = ixr - fx0, wy1 = iyr - fy0;
                        const int ix0 = (int)fx0, iy0 = (int)fy0;
                        const float mx0 = (ix0 >= 0 && ix0 < 16) ? 1.f - wx1 : 0.f;
                        const float mx1 = (ix0 + 1 >= 0 && ix0 + 1 < 16) ? wx1 : 0.f;
                        const float my0 = (iy0 >= 0 && iy0 < 16) ? 1.f - wy1 : 0.f;
                        const float my1 = (iy0 + 1 >= 0 && iy0 + 1 < 16) ? wy1 : 0.f;
                        const int cx0 = min(max(ix0, 0), 15), cx1 = min(max(ix0 + 1, 0), 15);
                        const int cy0 = min(max(iy0, 0), 15), cy1 = min(max(iy0 + 1, 0), 15);
                        const h4 v00 = sj[cy0 * 16 + cx0], v01 = sj[cy0 * 16 + cx1];
                        const h4 v10 = sj[cy1 * 16 + cx0], v11 = sj[cy1 * 16 + cx1];
                        const h4 frq = (v00 * splat4h(mx0) + v01 * splat4h(mx1)) * splat4h(my0)
                                     + (v10 * splat4h(mx0) + v11 * splat4h(mx1)) * splat4h(my1);
                        fr_w[px0 + q] = frq;
                    }
                    __builtin_amdgcn_wave_barrier();  // fr writes before fr reads

                    // ---- stage 2: translation sample of fr ----
                    const float dx = 0.25f * row0.w;
                    const float dy = -0.25f * row1.w;
                    const float fdx = floorf(dx), fdy = floorf(dy);
                    const float tx1 = dx - fdx, tx0 = 1.f - tx1;
                    const float ty1 = dy - fdy, ty0 = 1.f - ty1;
                    const int sdx = (int)fdx, sdy = (int)fdy;
                    const int oy = qy + sdy;
                    const bool iny0 = (oy >= 0) && (oy < 16);
                    const bool iny1 = (oy + 1 >= 0) && (oy + 1 < 16);
                    const float wya = iny0 ? ty0 : 0.f;
                    const float wyb = iny1 ? ty1 : 0.f;
                    const int cya = min(max(oy, 0), 15), cyb = min(max(oy + 1, 0), 15);
#pragma unroll
                    for (int q = 0; q < 4; ++q) {
                        const int ox = qx + q + sdx;
                        const bool inx0 = (ox >= 0) && (ox < 16);
                        const bool inx1 = (ox + 1 >= 0) && (ox + 1 < 16);
                        const float wxa = inx0 ? tx0 : 0.f;
                        const float wxb = inx1 ? tx1 : 0.f;
                        const int cxa = min(max(ox, 0), 15), cxb = min(max(ox + 1, 0), 15);
                        const h4 t00 = fr_w[cya * 16 + cxa], t01 = fr_w[cya * 16 + cxb];
                        const h4 t10 = fr_w[cyb * 16 + cxa], t11 = fr_w[cyb * 16 + cxb];
                        pair_acc[q] += (t00 * splat4h(wxa) + t01 * splat4h(wxb)) * splat4h(wya)
                                     + (t10 * splat4h(wxa) + t11 * splat4h(wxb)) * splat4h(wyb);
                    }
                    __builtin_amdgcn_wave_barrier();  // fr reads before next pair's writes
                }
            }
#pragma unroll
            for (int q = 0; q < 4; ++q)
#pragma unroll
                for (int k = 0; k < 4; ++k)
                    acc[k][q] += (float)pair_acc[q][k];
        }

        // store fused[b][i] -> out[i*B+b] (dwordx4 per channel)
        float* dst = out + (size_t)((i * NB + b) * NC + c0) * HW + px0;
#pragma unroll
        for (int k = 0; k < 4; ++k) *(f4*)(dst + k * HW) = acc[k];
        __builtin_amdgcn_wave_barrier();  // this item's LDS reads before next item's writes
    }
}

extern "C" void kernel_launch(void* const* d_in, const int* in_sizes, int n_in,
                              void* d_out, int out_size, void* d_ws, size_t ws_size,
                              hipStream_t stream) {
    const float* feat  = (const float*)d_in[0];
    const float* trans = (const float*)d_in[1];
    const int*   numa  = (const int*)d_in[2];
    float* out = (float*)d_out;

    fafmimo_wave_kernel<<<dim3(NBLK), dim3(256), 0, stream>>>(
        feat, trans, numa, out);
}